// Round 6
// baseline (148.944 us; speedup 1.0000x reference)
//
#include <hip/hip_runtime.h>
#include <hip/hip_bf16.h>
#include <math.h>

#define N 4096
#define K 2048
#define NC 32
#define MARGIN 0.3f

#define SPLITK 8
#define KC (K / SPLITK)   // 256 k-elements per item
#define GRID_A 512
#define GRID_B 256
#define MAXTILES 512

typedef float f32x4 __attribute__((ext_vector_type(4)));
typedef __bf16 bf16x8 __attribute__((ext_vector_type(8)));

__device__ __forceinline__ void glds16(const void* g, void* l) {
  __builtin_amdgcn_global_load_lds(
      (const __attribute__((address_space(1))) void*)g,
      (__attribute__((address_space(3))) void*)l, 16, 0, 0);
}

__device__ __forceinline__ int imin(int a, int b) { return a < b ? a : b; }

// ---------------------------------------------------------------------------
// Kernel 0: planner. Histogram -> offsets/cursors, row0_has_zero flag,
// done=0, and the 64x64 tile work-list (same as R5).
// Tile desc int4: x = i0 | (flags<<28) [bit0=diag, bit1=colside],
//                 y = j0, z = iend, w = jend (sorted-row space).
// ---------------------------------------------------------------------------
__global__ __launch_bounds__(256) void plan_kernel(
    const int* __restrict__ tg, int* __restrict__ cursor,
    int* __restrict__ flag, int* __restrict__ done, int* __restrict__ Tp,
    int4* __restrict__ tiles) {
  __shared__ int h[NC], soff[NC], stb[NC + 1];
  int t = threadIdx.x;
  if (t < NC) h[t] = 0;
  __syncthreads();
  const int4* tg4 = (const int4*)tg;
  for (int i = t; i < N / 4; i += 256) {
    int4 v = tg4[i];
    atomicAdd(&h[v.x], 1); atomicAdd(&h[v.y], 1);
    atomicAdd(&h[v.z], 1); atomicAdd(&h[v.w], 1);
  }
  __syncthreads();
  if (t == 0) {
    int acc = 0, tacc = 0;
    for (int c = 0; c < NC; c++) {
      int n = h[c];
      soff[c] = acc;
      cursor[c] = acc;
      acc += n;
      stb[c] = tacc;
      int tt = (n + 63) >> 6;
      tacc += (tt * (tt + 1)) >> 1;
    }
    stb[NC] = tacc;
    int n0 = h[0], nz = N - n0;
    int t0b = (n0 + 63) >> 6, tzb = (nz + 63) >> 6;
    int T = tacc + ((n0 > 0 && nz > 0) ? t0b * tzb : 0);
    Tp[0] = imin(T, MAXTILES);
    flag[0] = (tg[0] == 0) ? (nz > 0) : (n0 > 0);
    done[0] = 0;
  }
  __syncthreads();
  if (t < NC && h[t] > 0) {
    int n = h[t], o = soff[t];
    int tt = (n + 63) >> 6;
    int idx = stb[t];
    for (int si = 0; si < tt; si++)
      for (int sj = si; sj < tt; sj++) {
        int fl = (si < sj) ? 3 : 1;
        if (idx < MAXTILES)
          tiles[idx] = make_int4((o + si * 64) | (fl << 28), o + sj * 64,
                                 o + n, o + n);
        idx++;
      }
  }
  int n0 = h[0], nz = N - n0;
  if (n0 > 0 && nz > 0) {
    int t0b = (n0 + 63) >> 6, tzb = (nz + 63) >> 6;
    int base = stb[NC];
    for (int k2 = t; k2 < t0b * tzb; k2 += 256) {
      int si = k2 / tzb, sj = k2 - si * tzb;
      if (base + k2 < MAXTILES)
        tiles[base + k2] =
            make_int4((si * 64) | (2 << 28), n0 + sj * 64, n0, N);
    }
  }
}

// ---------------------------------------------------------------------------
// Kernel 1: fp32 -> bf16 convert + class-sorted scatter + sum-of-squares +
// ap/an init. One block per original row.
// ---------------------------------------------------------------------------
__global__ __launch_bounds__(256) void convert_kernel(
    const float* __restrict__ X, const int* __restrict__ tg,
    __bf16* __restrict__ Xg, float* __restrict__ sqg,
    unsigned int* __restrict__ ap, unsigned int* __restrict__ an,
    int* __restrict__ cursor) {
  int row = blockIdx.x;
  int t = threadIdx.x;
  const float* xr = X + (size_t)row * K;

  float4 v0 = ((const float4*)xr)[t * 2 + 0];
  float4 v1 = ((const float4*)xr)[t * 2 + 1];

  float s = v0.x * v0.x + v0.y * v0.y + v0.z * v0.z + v0.w * v0.w +
            v1.x * v1.x + v1.y * v1.y + v1.z * v1.z + v1.w * v1.w;

  bf16x8 b;
  b[0] = (__bf16)v0.x; b[1] = (__bf16)v0.y; b[2] = (__bf16)v0.z; b[3] = (__bf16)v0.w;
  b[4] = (__bf16)v1.x; b[5] = (__bf16)v1.y; b[6] = (__bf16)v1.z; b[7] = (__bf16)v1.w;

  #pragma unroll
  for (int m = 32; m; m >>= 1) s += __shfl_xor(s, m);

  __shared__ float wred[4];
  __shared__ int spos;
  if ((t & 63) == 0) wred[t >> 6] = s;
  if (t == 0) spos = atomicAdd(&cursor[tg[row]], 1);
  __syncthreads();
  int pos = spos;

  ((bf16x8*)(Xg + (size_t)pos * K))[t] = b;
  if (t == 0) {
    sqg[pos] = wred[0] + wred[1] + wred[2] + wred[3];
    ap[pos] = 0u;           // identity for max of non-negative
    an[pos] = 0x7f800000u;  // +inf
  }
}

// ---------------------------------------------------------------------------
// Kernel 2 (phase A): split-K partial Gram. Item m = (tile m>>3, split m&7).
// Stage ALL 4 BK=64 stages up-front (16 loads/thread in flight), then
// progressive vmcnt waits. Partial C stored raw (16 fp32/thread, coalesced).
// ---------------------------------------------------------------------------
__global__ __launch_bounds__(256, 2) void gemm_partial_kernel(
    const __bf16* __restrict__ Xg, const int* __restrict__ Tp,
    const int4* __restrict__ tiles, float* __restrict__ pg) {
  __shared__ __align__(16) char sAB[4][16384];  // 64 KiB -> 2 blocks/CU

  int t = threadIdx.x;
  int w = t >> 6, l = t & 63;
  int wi = w >> 1, wj = w & 1;
  int quad = l >> 4, lr = l & 15;

  // Fragment LDS byte offsets (item-invariant). Row stride 128B; chunk
  // ch = h*4+quad stored at slot ch ^ (row&7), row&7 == lr&7.
  int aoff[2][2], boff[2][2];
  #pragma unroll
  for (int ti2 = 0; ti2 < 2; ti2++)
    #pragma unroll
    for (int h = 0; h < 2; h++) {
      int sw = (((h << 2) + quad) ^ (lr & 7)) << 4;
      aoff[ti2][h] = (wi * 32 + ti2 * 16 + lr) * 128 + sw;
      boff[ti2][h] = (wj * 32 + ti2 * 16 + lr) * 128 + sw + 8192;
    }

  int rr = t >> 3, slot = t & 7;
  int M = Tp[0] * SPLITK;

  for (int m = blockIdx.x; m < M; m += GRID_A) {
    int tid = m >> 3, s = m & 7;
    int4 dsc = tiles[tid];
    int i0 = dsc.x & 0x0FFFFFFF;
    int j0 = dsc.y, iend = dsc.z, jend = dsc.w;

    const char* gA[2]; const char* gB[2];
    #pragma unroll
    for (int r = 0; r < 2; r++) {
      int row_l = r * 32 + rr;
      int cbg = slot ^ (row_l & 7);
      int ia = imin(i0 + row_l, iend - 1);
      int ja = imin(j0 + row_l, jend - 1);
      gA[r] = (const char*)(Xg + (size_t)ia * K) + s * (KC * 2) + cbg * 16;
      gB[r] = (const char*)(Xg + (size_t)ja * K) + s * (KC * 2) + cbg * 16;
    }

    __syncthreads();  // protect LDS from previous item (drains vmcnt too)

    #pragma unroll
    for (int st = 0; st < 4; st++) {
      char* base = sAB[st] + t * 16;
      int koff = st * 128;
      glds16(gA[0] + koff, base);
      glds16(gA[1] + koff, base + 4096);
      glds16(gB[0] + koff, base + 8192);
      glds16(gB[1] + koff, base + 12288);
    }

    f32x4 acc[2][2];
    acc[0][0] = (f32x4)0.f; acc[0][1] = (f32x4)0.f;
    acc[1][0] = (f32x4)0.f; acc[1][1] = (f32x4)0.f;

    auto compute = [&](int st) {
      const char* base = sAB[st];
      bf16x8 af[2][2], bfr[2][2];
      #pragma unroll
      for (int ti2 = 0; ti2 < 2; ti2++)
        #pragma unroll
        for (int h = 0; h < 2; h++) {
          af[ti2][h] = *(const bf16x8*)(base + aoff[ti2][h]);
          bfr[ti2][h] = *(const bf16x8*)(base + boff[ti2][h]);
        }
      #pragma unroll
      for (int h = 0; h < 2; h++)
        #pragma unroll
        for (int ti2 = 0; ti2 < 2; ti2++)
          #pragma unroll
          for (int tj2 = 0; tj2 < 2; tj2++)
            acc[ti2][tj2] = __builtin_amdgcn_mfma_f32_16x16x32_bf16(
                af[ti2][h], bfr[tj2][h], acc[ti2][tj2], 0, 0, 0);
    };

    __builtin_amdgcn_s_waitcnt(0x0F7C);  // vmcnt(12): stage 0 landed
    __builtin_amdgcn_s_barrier();
    compute(0);
    __builtin_amdgcn_s_waitcnt(0x0F78);  // vmcnt(8): stage 1 landed
    __builtin_amdgcn_s_barrier();
    compute(1);
    __builtin_amdgcn_s_waitcnt(0x0F74);  // vmcnt(4): stage 2 landed
    __builtin_amdgcn_s_barrier();
    compute(2);
    __builtin_amdgcn_s_waitcnt(0x0F70);  // vmcnt(0): stage 3 landed
    __builtin_amdgcn_s_barrier();
    compute(3);

    f32x4* dst = (f32x4*)(pg + (size_t)m * 4096 + t * 16);
    dst[0] = acc[0][0]; dst[1] = acc[0][1];
    dst[2] = acc[1][0]; dst[3] = acc[1][1];
  }
}

// ---------------------------------------------------------------------------
// Kernel 3 (phase B): sum the 8 partials per tile, distance/mask epilogue
// (identical math to R5), ticket -> final loss.
// ---------------------------------------------------------------------------
__global__ __launch_bounds__(256) void reduce_kernel(
    const float* __restrict__ pg, const float* __restrict__ sq,
    const int* __restrict__ Tp, const int4* __restrict__ tiles,
    const int* __restrict__ flag, int* __restrict__ done,
    unsigned int* __restrict__ ap, unsigned int* __restrict__ an,
    float* __restrict__ out) {
  __shared__ int s_islast;
  __shared__ float wred[4];

  int t = threadIdx.x;
  int w = t >> 6, l = t & 63;
  int wi = w >> 1, wj = w & 1;
  int quad = l >> 4, lr = l & 15;
  int T = Tp[0];

  for (int tid = blockIdx.x; tid < T; tid += GRID_B) {
    int4 dsc = tiles[tid];
    unsigned fl = (unsigned)dsc.x >> 28;
    int i0 = dsc.x & 0x0FFFFFFF;
    int j0 = dsc.y, iend = dsc.z, jend = dsc.w;
    bool diag = fl & 1, colside = (fl & 2) != 0;

    f32x4 acc[2][2];
    acc[0][0] = (f32x4)0.f; acc[0][1] = (f32x4)0.f;
    acc[1][0] = (f32x4)0.f; acc[1][1] = (f32x4)0.f;
    const float* base = pg + (size_t)tid * (SPLITK * 4096) + t * 16;
    #pragma unroll
    for (int s = 0; s < SPLITK; s++) {
      const f32x4* p = (const f32x4*)(base + (size_t)s * 4096);
      acc[0][0] += p[0]; acc[0][1] += p[1];
      acc[1][0] += p[2]; acc[1][1] += p[3];
    }

    int jgc[2]; float sqj[2];
    #pragma unroll
    for (int tj2 = 0; tj2 < 2; tj2++) {
      jgc[tj2] = imin(j0 + wj * 32 + tj2 * 16 + lr, jend - 1);
      sqj[tj2] = sq[jgc[tj2]];
    }
    float cred[2];
    cred[0] = cred[1] = diag ? 0.f : INFINITY;

    #pragma unroll
    for (int ti2 = 0; ti2 < 2; ti2++) {
      #pragma unroll
      for (int r = 0; r < 4; r++) {
        int ir = imin(i0 + wi * 32 + ti2 * 16 + quad * 4 + r, iend - 1);
        float sqi = sq[ir];
        float v = diag ? 0.f : INFINITY;
        #pragma unroll
        for (int tj2 = 0; tj2 < 2; tj2++) {
          float d2 = fmaxf(sqi + sqj[tj2] - 2.f * acc[ti2][tj2][r], 1e-12f);
          v = diag ? fmaxf(v, d2) : fminf(v, d2);
          cred[tj2] = diag ? fmaxf(cred[tj2], d2) : fminf(cred[tj2], d2);
        }
        #pragma unroll
        for (int m = 1; m < 16; m <<= 1) {
          float o = __shfl_xor(v, m);
          v = diag ? fmaxf(v, o) : fminf(v, o);
        }
        if (lr == 0) {
          unsigned int u = __float_as_uint(sqrtf(v));
          if (diag) atomicMax(ap + ir, u);
          else      atomicMin(an + ir, u);
        }
      }
    }
    if (colside) {
      #pragma unroll
      for (int tj2 = 0; tj2 < 2; tj2++) {
        float v = cred[tj2];
        float o = __shfl_xor(v, 16);
        v = diag ? fmaxf(v, o) : fminf(v, o);
        o = __shfl_xor(v, 32);
        v = diag ? fmaxf(v, o) : fminf(v, o);
        if (quad == 0) {
          unsigned int u = __float_as_uint(sqrtf(v));
          if (diag) atomicMax(ap + jgc[tj2], u);
          else      atomicMin(an + jgc[tj2], u);
        }
      }
    }
  }

  // ---- last-block ticket: final loss reduction --------------------------
  __syncthreads();
  if (t == 0) {
    __threadfence();
    int ticket = __hip_atomic_fetch_add(done, 1, __ATOMIC_ACQ_REL,
                                        __HIP_MEMORY_SCOPE_AGENT);
    s_islast = (ticket == GRID_B - 1);
  }
  __syncthreads();
  if (s_islast) {
    int has = flag[0];
    float s = 0.f;
    for (int i = t; i < N; i += 256) {
      unsigned int au = __hip_atomic_load(ap + i, __ATOMIC_RELAXED,
                                          __HIP_MEMORY_SCOPE_AGENT);
      unsigned int nu = __hip_atomic_load(an + i, __ATOMIC_RELAXED,
                                          __HIP_MEMORY_SCOPE_AGENT);
      float a = __uint_as_float(au);
      float bb = has ? __uint_as_float(nu) : 0.f;
      s += fmaxf(a - bb + MARGIN, 0.f);
    }
    #pragma unroll
    for (int m = 32; m; m >>= 1) s += __shfl_xor(s, m);
    if ((t & 63) == 0) wred[t >> 6] = s;
    __syncthreads();
    if (t == 0) out[0] = (wred[0] + wred[1] + wred[2] + wred[3]) / (float)N;
  }
}

// ---------------------------------------------------------------------------
extern "C" void kernel_launch(void* const* d_in, const int* in_sizes, int n_in,
                              void* d_out, int out_size, void* d_ws,
                              size_t ws_size, hipStream_t stream) {
  const float* X = (const float*)d_in[0];
  const int* tg = (const int*)d_in[1];
  float* out = (float*)d_out;

  char* ws = (char*)d_ws;
  __bf16* Xg = (__bf16*)ws;
  size_t o = (size_t)N * K * 2;
  float* sq = (float*)(ws + o); o += (size_t)N * 4;
  unsigned int* ap = (unsigned int*)(ws + o); o += (size_t)N * 4;
  unsigned int* an = (unsigned int*)(ws + o); o += (size_t)N * 4;
  int* cursor = (int*)(ws + o); o += NC * 4;
  int* flag = (int*)(ws + o); o += 4;
  int* done = (int*)(ws + o); o += 4;
  int* Tp = (int*)(ws + o); o += 4;
  o = (o + 255) & ~(size_t)255;
  int4* tiles = (int4*)(ws + o); o += (size_t)MAXTILES * 16;
  o = (o + 255) & ~(size_t)255;
  float* pg = (float*)(ws + o);  // up to 512 tiles * 8 * 16KB = 64 MiB

  plan_kernel<<<1, 256, 0, stream>>>(tg, cursor, flag, done, Tp, tiles);
  convert_kernel<<<N, 256, 0, stream>>>(X, tg, Xg, sq, ap, an, cursor);
  gemm_partial_kernel<<<GRID_A, 256, 0, stream>>>(Xg, Tp, tiles, pg);
  reduce_kernel<<<GRID_B, 256, 0, stream>>>(pg, sq, Tp, tiles, flag, done,
                                            ap, an, out);
}